// Round 2
// baseline (472.066 us; speedup 1.0000x reference)
//
#include <hip/hip_runtime.h>

constexpr int NN = 50000;        // nodes
constexpr int NE = 800000;       // edges (before self-loops)
constexpr int ET = NE + NN;      // edges + self-loops = 850000
constexpr int IC = 128;          // in channels
constexpr int HC = 256;          // heads * out_ch
constexpr int OC = 64;           // out channels
// heads = 4

// ---------------------------------------------------------------------------
// Kernel 1: x = feature @ lin_w  ->  X[N,256], fused per-node attention logits
// ---------------------------------------------------------------------------
__global__ __launch_bounds__(256) void proj_kernel(
    const float* __restrict__ feat, const float* __restrict__ lin_w,
    const float* __restrict__ att_s, const float* __restrict__ att_d,
    float* __restrict__ X, float* __restrict__ As, float* __restrict__ Ad)
{
    constexpr int TM = 16;
    __shared__ float sf[TM][IC];
    const int t  = threadIdx.x;          // output column 0..255 (h = t>>6, c = t&63)
    const int n0 = blockIdx.x * TM;

    for (int i = t; i < TM * IC; i += 256)
        sf[i >> 7][i & 127] = feat[(size_t)n0 * IC + i];
    __syncthreads();

    float acc[TM];
#pragma unroll
    for (int m = 0; m < TM; ++m) acc[m] = 0.f;

    for (int k = 0; k < IC; k += 4) {
        const float w0 = lin_w[(k + 0) * HC + t];
        const float w1 = lin_w[(k + 1) * HC + t];
        const float w2 = lin_w[(k + 2) * HC + t];
        const float w3 = lin_w[(k + 3) * HC + t];
#pragma unroll
        for (int m = 0; m < TM; ++m) {
            const float4 f = *reinterpret_cast<const float4*>(&sf[m][k]); // broadcast
            acc[m] = fmaf(w3, f.w, fmaf(w2, f.z, fmaf(w1, f.y, fmaf(w0, f.x, acc[m]))));
        }
    }

    const float as_t = att_s[t];
    const float ad_t = att_d[t];
    const int lane = t & 63;
    const int h    = t >> 6;

#pragma unroll
    for (int m = 0; m < TM; ++m) {
        X[(size_t)(n0 + m) * HC + t] = acc[m];
        float vs = acc[m] * as_t;
        float vd = acc[m] * ad_t;
#pragma unroll
        for (int off = 32; off; off >>= 1) {
            vs += __shfl_down(vs, off);
            vd += __shfl_down(vd, off);
        }
        if (lane == 0) {
            As[(n0 + m) * 4 + h] = vs;
            Ad[(n0 + m) * 4 + h] = vd;
        }
    }
}

// ---------------------------------------------------------------------------
// Kernel 2: per-edge logits (segment_max skipped: softmax shift-invariant,
// |logit| small enough that fp32 exp cannot overflow).
// ---------------------------------------------------------------------------
__global__ __launch_bounds__(256) void edge_kernel(
    const int* __restrict__ ei, const float* __restrict__ As,
    const float* __restrict__ Ad, float* __restrict__ Ex,
    float* __restrict__ Den)
{
    const int e = blockIdx.x * 256 + threadIdx.x;
    if (e >= ET) return;
    int s, d;
    if (e < NE) { s = ei[e]; d = ei[NE + e]; }
    else        { s = e - NE; d = s; }

    const float4 a = *reinterpret_cast<const float4*>(&As[(size_t)s * 4]);
    const float4 b = *reinterpret_cast<const float4*>(&Ad[(size_t)d * 4]);
    float4 al;
    al.x = a.x + b.x; al.y = a.y + b.y; al.z = a.z + b.z; al.w = a.w + b.w;
    al.x = al.x > 0.f ? al.x : 0.2f * al.x;
    al.y = al.y > 0.f ? al.y : 0.2f * al.y;
    al.z = al.z > 0.f ? al.z : 0.2f * al.z;
    al.w = al.w > 0.f ? al.w : 0.2f * al.w;
    float4 ex;
    ex.x = __expf(al.x); ex.y = __expf(al.y);
    ex.z = __expf(al.z); ex.w = __expf(al.w);
    *reinterpret_cast<float4*>(&Ex[(size_t)e * 4]) = ex;
    atomicAdd(&Den[d * 4 + 0], ex.x);
    atomicAdd(&Den[d * 4 + 1], ex.y);
    atomicAdd(&Den[d * 4 + 2], ex.z);
    atomicAdd(&Den[d * 4 + 3], ex.w);
}

// ---------------------------------------------------------------------------
// Kernel 3: scatter. One 64-lane wave per edge; lane = output channel.
// Heads reduced in-register (weights fold the 1/4 head-mean) -> ONE atomic
// per lane, 64 contiguous atomics per wave.
// ---------------------------------------------------------------------------
__global__ __launch_bounds__(256) void scatter_kernel(
    const int* __restrict__ ei, const float* __restrict__ X,
    const float* __restrict__ Ex, const float* __restrict__ Den,
    float* __restrict__ Acc)
{
    const int gid  = blockIdx.x * 256 + threadIdx.x;
    const int e    = gid >> 6;
    const int lane = gid & 63;
    if (e >= ET) return;
    int s, d;
    if (e < NE) { s = ei[e]; d = ei[NE + e]; }
    else        { s = e - NE; d = s; }

    const float4 ex = *reinterpret_cast<const float4*>(&Ex[(size_t)e * 4]);
    const float4 dn = *reinterpret_cast<const float4*>(&Den[(size_t)d * 4]);
    const float w0 = 0.25f * __fdividef(ex.x, dn.x);
    const float w1 = 0.25f * __fdividef(ex.y, dn.y);
    const float w2 = 0.25f * __fdividef(ex.z, dn.z);
    const float w3 = 0.25f * __fdividef(ex.w, dn.w);

    const float* xr = X + (size_t)s * HC;
    const float v = w0 * xr[lane] + w1 * xr[64 + lane] +
                    w2 * xr[128 + lane] + w3 * xr[192 + lane];
    atomicAdd(&Acc[(size_t)d * OC + lane], v);
}

// ---------------------------------------------------------------------------
// Kernel 4: out = Acc + bias  (fully overwrites d_out each call)
// ---------------------------------------------------------------------------
__global__ __launch_bounds__(256) void finalize_kernel(
    const float* __restrict__ Acc, const float* __restrict__ bias,
    float* __restrict__ out)
{
    const int i = blockIdx.x * 256 + threadIdx.x;
    if (i < NN * OC) out[i] = Acc[i] + bias[i & 63];
}

extern "C" void kernel_launch(void* const* d_in, const int* in_sizes, int n_in,
                              void* d_out, int out_size, void* d_ws, size_t ws_size,
                              hipStream_t stream)
{
    const float* feat = (const float*)d_in[0];
    const int*   ei   = (const int*)d_in[1];   // [2, NE]
    const float* lw   = (const float*)d_in[2];
    const float* as   = (const float*)d_in[3];
    const float* ad   = (const float*)d_in[4];
    const float* bias = (const float*)d_in[5];
    float* out = (float*)d_out;

    float* ws   = (float*)d_ws;
    float* X    = ws;                          // NN*256
    float* Asrc = X    + (size_t)NN * HC;      // NN*4
    float* Adst = Asrc + (size_t)NN * 4;       // NN*4
    float* Ex   = Adst + (size_t)NN * 4;       // ET*4
    float* Den  = Ex   + (size_t)ET * 4;       // NN*4   (zeroed)
    float* Acc  = Den  + (size_t)NN * 4;       // NN*64  (zeroed, adjacent)

    (void)hipMemsetAsync(Den, 0, sizeof(float) * (size_t)NN * (4 + OC), stream);

    proj_kernel<<<NN / 16, 256, 0, stream>>>(feat, lw, as, ad, X, Asrc, Adst);
    edge_kernel<<<(ET + 255) / 256, 256, 0, stream>>>(ei, Asrc, Adst, Ex, Den);
    scatter_kernel<<<((size_t)ET * 64 + 255) / 256, 256, 0, stream>>>(ei, X, Ex, Den, Acc);
    finalize_kernel<<<(NN * OC + 255) / 256, 256, 0, stream>>>(Acc, bias, out);
}

// Round 3
// 384.802 us; speedup vs baseline: 1.2268x; 1.2268x over previous
//
#include <hip/hip_runtime.h>
#include <hip/hip_fp16.h>

constexpr int NN = 50000;        // nodes
constexpr int NE = 800000;       // edges (before self-loops)
constexpr int ET = NE + NN;      // edges + self-loops = 850000
constexpr int IC = 128;          // in channels
constexpr int HC = 256;          // heads * out_ch
constexpr int OC = 64;           // out channels
// heads = 4

// ---------------------------------------------------------------------------
// Kernel 1: x = feature @ lin_w -> Xh[N,256] (fp16), fused per-node logits
// ---------------------------------------------------------------------------
__global__ __launch_bounds__(256) void proj_kernel(
    const float* __restrict__ feat, const float* __restrict__ lin_w,
    const float* __restrict__ att_s, const float* __restrict__ att_d,
    __half* __restrict__ Xh, float* __restrict__ As, float* __restrict__ Ad)
{
    constexpr int TM = 16;
    __shared__ float sf[TM][IC];
    const int t  = threadIdx.x;          // output column 0..255
    const int n0 = blockIdx.x * TM;

    for (int i = t; i < TM * IC; i += 256)
        sf[i >> 7][i & 127] = feat[(size_t)n0 * IC + i];
    __syncthreads();

    float acc[TM];
#pragma unroll
    for (int m = 0; m < TM; ++m) acc[m] = 0.f;

    for (int k = 0; k < IC; k += 4) {
        const float w0 = lin_w[(k + 0) * HC + t];
        const float w1 = lin_w[(k + 1) * HC + t];
        const float w2 = lin_w[(k + 2) * HC + t];
        const float w3 = lin_w[(k + 3) * HC + t];
#pragma unroll
        for (int m = 0; m < TM; ++m) {
            const float4 f = *reinterpret_cast<const float4*>(&sf[m][k]);
            acc[m] = fmaf(w3, f.w, fmaf(w2, f.z, fmaf(w1, f.y, fmaf(w0, f.x, acc[m]))));
        }
    }

    const float as_t = att_s[t];
    const float ad_t = att_d[t];
    const int lane = t & 63;
    const int h    = t >> 6;

#pragma unroll
    for (int m = 0; m < TM; ++m) {
        Xh[(size_t)(n0 + m) * HC + t] = __float2half(acc[m]);
        float vs = acc[m] * as_t;
        float vd = acc[m] * ad_t;
#pragma unroll
        for (int off = 32; off; off >>= 1) {
            vs += __shfl_down(vs, off);
            vd += __shfl_down(vd, off);
        }
        if (lane == 0) {
            As[(n0 + m) * 4 + h] = vs;
            Ad[(n0 + m) * 4 + h] = vd;
        }
    }
}

// ---------------------------------------------------------------------------
// CSR build: histogram over dst, single-block scan, fill (src ids sorted by dst)
// ---------------------------------------------------------------------------
__global__ __launch_bounds__(256) void hist_kernel(
    const int* __restrict__ ei, int* __restrict__ deg)
{
    const int e = blockIdx.x * 256 + threadIdx.x;
    if (e >= ET) return;
    const int d = (e < NE) ? ei[NE + e] : (e - NE);
    atomicAdd(&deg[d], 1);
}

__global__ __launch_bounds__(1024) void scan_kernel(
    const int* __restrict__ deg, int* __restrict__ rowptr, int* __restrict__ cursor)
{
    __shared__ int part[1024];
    const int t = threadIdx.x;
    constexpr int CH = (NN + 1023) / 1024;   // 49
    const int base = t * CH;
    int s = 0;
    for (int i = 0; i < CH; ++i) {
        const int idx = base + i;
        if (idx < NN) s += deg[idx];
    }
    part[t] = s;
    __syncthreads();
    for (int off = 1; off < 1024; off <<= 1) {
        const int v = (t >= off) ? part[t - off] : 0;
        __syncthreads();
        part[t] += v;
        __syncthreads();
    }
    int excl = (t == 0) ? 0 : part[t - 1];
    for (int i = 0; i < CH; ++i) {
        const int idx = base + i;
        if (idx < NN) {
            rowptr[idx] = excl;
            cursor[idx] = excl;
            excl += deg[idx];
        }
    }
    if (t == 1023) rowptr[NN] = part[1023];
}

__global__ __launch_bounds__(256) void fill_kernel(
    const int* __restrict__ ei, int* __restrict__ cursor, int* __restrict__ csr_src)
{
    const int e = blockIdx.x * 256 + threadIdx.x;
    if (e >= ET) return;
    int s, d;
    if (e < NE) { s = ei[e]; d = ei[NE + e]; }
    else        { s = e - NE; d = s; }
    const int pos = atomicAdd(&cursor[d], 1);
    csr_src[pos] = s;
}

// ---------------------------------------------------------------------------
// Gather: one 64-lane wave per dst node. lane l holds channels 4*(l&15)..+3 of
// head l>>4 (one 8B fp16 load per edge -> 512B coalesced per wave). ex computed
// inline; normalization is linear so den accumulates alongside. No atomics.
// Epilogue: per-head normalize, cross-head shfl_xor sum, +bias, write out.
// ---------------------------------------------------------------------------
__global__ __launch_bounds__(256) void gather_kernel(
    const int* __restrict__ rowptr, const int* __restrict__ csr_src,
    const float* __restrict__ As, const float* __restrict__ Ad,
    const __half* __restrict__ Xh, const float* __restrict__ bias,
    float* __restrict__ out)
{
    const int gid  = blockIdx.x * 256 + threadIdx.x;
    const int w    = gid >> 6;          // dst node
    const int lane = gid & 63;
    if (w >= NN) return;

    const int beg = rowptr[w];
    const int end = rowptr[w + 1];
    const int h   = lane >> 4;

    const float4 ad = *reinterpret_cast<const float4*>(&Ad[(size_t)w * 4]);
    float4 acc = {0.f, 0.f, 0.f, 0.f};
    float4 den = {0.f, 0.f, 0.f, 0.f};

    int sj = (beg < end) ? csr_src[beg] : 0;
    for (int j = beg; j < end; ++j) {
        const int s = sj;
        if (j + 1 < end) sj = csr_src[j + 1];   // prefetch next src

        const float4 a = *reinterpret_cast<const float4*>(&As[(size_t)s * 4]);
        float4 t;
        t.x = a.x + ad.x; t.y = a.y + ad.y; t.z = a.z + ad.z; t.w = a.w + ad.w;
        t.x = t.x > 0.f ? t.x : 0.2f * t.x;
        t.y = t.y > 0.f ? t.y : 0.2f * t.y;
        t.z = t.z > 0.f ? t.z : 0.2f * t.z;
        t.w = t.w > 0.f ? t.w : 0.2f * t.w;
        float4 ex;
        ex.x = __expf(t.x); ex.y = __expf(t.y);
        ex.z = __expf(t.z); ex.w = __expf(t.w);
        den.x += ex.x; den.y += ex.y; den.z += ex.z; den.w += ex.w;

        const float exh = (h < 2) ? (h == 0 ? ex.x : ex.y)
                                  : (h == 2 ? ex.z : ex.w);

        // 8B = 4 fp16 channels per lane, 512B coalesced per wave
        const float2 raw = *reinterpret_cast<const float2*>(
            Xh + (size_t)s * HC + 4 * lane);
        const __half2* h2 = reinterpret_cast<const __half2*>(&raw);
        const float2 lo = __half22float2(h2[0]);
        const float2 hi = __half22float2(h2[1]);
        acc.x = fmaf(exh, lo.x, acc.x);
        acc.y = fmaf(exh, lo.y, acc.y);
        acc.z = fmaf(exh, hi.x, acc.z);
        acc.w = fmaf(exh, hi.y, acc.w);
    }

    const float dh  = (h < 2) ? (h == 0 ? den.x : den.y)
                              : (h == 2 ? den.z : den.w);
    const float inv = 0.25f * __frcp_rn(dh);
    acc.x *= inv; acc.y *= inv; acc.z *= inv; acc.w *= inv;

    // sum across the 4 head-lane-groups (lanes l, l^16, l^32, l^48 share channels)
    acc.x += __shfl_xor(acc.x, 16); acc.x += __shfl_xor(acc.x, 32);
    acc.y += __shfl_xor(acc.y, 16); acc.y += __shfl_xor(acc.y, 32);
    acc.z += __shfl_xor(acc.z, 16); acc.z += __shfl_xor(acc.z, 32);
    acc.w += __shfl_xor(acc.w, 16); acc.w += __shfl_xor(acc.w, 32);

    if (lane < 16) {
        const float4 b = *reinterpret_cast<const float4*>(&bias[4 * lane]);
        float4 o;
        o.x = acc.x + b.x; o.y = acc.y + b.y;
        o.z = acc.z + b.z; o.w = acc.w + b.w;
        *reinterpret_cast<float4*>(&out[(size_t)w * OC + 4 * lane]) = o;
    }
}

extern "C" void kernel_launch(void* const* d_in, const int* in_sizes, int n_in,
                              void* d_out, int out_size, void* d_ws, size_t ws_size,
                              hipStream_t stream)
{
    const float* feat = (const float*)d_in[0];
    const int*   ei   = (const int*)d_in[1];   // [2, NE]
    const float* lw   = (const float*)d_in[2];
    const float* as   = (const float*)d_in[3];
    const float* ad   = (const float*)d_in[4];
    const float* bias = (const float*)d_in[5];
    float* out = (float*)d_out;

    char* ws = (char*)d_ws;
    __half* Xh     = (__half*)ws;                     ws += (size_t)NN * HC * 2;  // 25.6MB
    float*  Asrc   = (float*)ws;                      ws += (size_t)NN * 4 * 4;
    float*  Adst   = (float*)ws;                      ws += (size_t)NN * 4 * 4;
    int*    deg    = (int*)ws;                        ws += (size_t)NN * 4;       // zeroed
    int*    rowptr = (int*)ws;                        ws += (size_t)(NN + 1) * 4;
    int*    cursor = (int*)ws;                        ws += (size_t)NN * 4;
    int*    csrsrc = (int*)ws;                        ws += (size_t)ET * 4;

    (void)hipMemsetAsync(deg, 0, sizeof(int) * (size_t)NN, stream);

    proj_kernel<<<NN / 16, 256, 0, stream>>>(feat, lw, as, ad, Xh, Asrc, Adst);
    hist_kernel<<<(ET + 255) / 256, 256, 0, stream>>>(ei, deg);
    scan_kernel<<<1, 1024, 0, stream>>>(deg, rowptr, cursor);
    fill_kernel<<<(ET + 255) / 256, 256, 0, stream>>>(ei, cursor, csrsrc);
    gather_kernel<<<(NN * 64 + 255) / 256, 256, 0, stream>>>(
        rowptr, csrsrc, Asrc, Adst, Xh, bias, out);
}

// Round 4
// 222.060 us; speedup vs baseline: 2.1258x; 1.7329x over previous
//
#include <hip/hip_runtime.h>
#include <hip/hip_fp16.h>

typedef _Float16 f16x8 __attribute__((ext_vector_type(8)));
typedef float    f32x4 __attribute__((ext_vector_type(4)));

constexpr int NN = 50000;        // nodes
constexpr int NE = 800000;       // edges (before self-loops)
constexpr int ET = NE + NN;      // edges + self-loops
constexpr int IC = 128;          // in channels
constexpr int HC = 256;          // heads * out_ch
constexpr int OC = 64;           // out channels

// ---------------------------------------------------------------------------
// Prep: Wt[m][k] = lin_w[k][m] as fp16 (A-operand, L2-resident 64KB)
// ---------------------------------------------------------------------------
__global__ void prep_wt(const float* __restrict__ w, __half* __restrict__ wt)
{
    const int k = blockIdx.x;      // 128
    const int m = threadIdx.x;     // 256
    wt[m * IC + k] = __float2half(w[k * HC + m]);
}

// ---------------------------------------------------------------------------
// Proj via MFMA: per block 64 nodes x 256 channels, K=128.
// feat tile staged in LDS fp16, XOR-swizzled 16B chunks (16 chunks/row).
// Wave w covers channels 64w..64w+63.  A: Wt rows (channels), B: feat nodes.
// ---------------------------------------------------------------------------
__global__ __launch_bounds__(256) void proj_mfma(
    const float* __restrict__ feat, const __half* __restrict__ wt,
    __half* __restrict__ Xh)
{
    __shared__ _Float16 sf[64 * 128];
    const int t  = threadIdx.x;
    const int w  = t >> 6;
    const int l  = t & 63;
    const int n0 = blockIdx.x * 64;

    // cooperative load: thread t covers 16B-chunks 4*(t&3)..+3 of row t>>2
    {
        const int r  = t >> 2;
        const int gr = min(n0 + r, NN - 1);
        const float* src = feat + (size_t)gr * IC + (t & 3) * 32;
#pragma unroll
        for (int i = 0; i < 4; ++i) {
            const float4 f0 = *reinterpret_cast<const float4*>(src + i * 8);
            const float4 f1 = *reinterpret_cast<const float4*>(src + i * 8 + 4);
            f16x8 hv;
            hv[0] = (_Float16)f0.x; hv[1] = (_Float16)f0.y;
            hv[2] = (_Float16)f0.z; hv[3] = (_Float16)f0.w;
            hv[4] = (_Float16)f1.x; hv[5] = (_Float16)f1.y;
            hv[6] = (_Float16)f1.z; hv[7] = (_Float16)f1.w;
            const int cc = (t & 3) * 4 + i;
            *reinterpret_cast<f16x8*>(&sf[(r * 16 + (cc ^ (r & 7))) * 8]) = hv;
        }
    }
    __syncthreads();

    const int lhi = l >> 4, llo = l & 15;
    f32x4 acc[4][4] = {};   // [mg(channel)][ng(node)]

#pragma unroll
    for (int ks = 0; ks < 4; ++ks) {
        f16x8 a[4], b[4];
#pragma unroll
        for (int mg = 0; mg < 4; ++mg) {
            const int row = w * 64 + mg * 16 + llo;            // channel
            a[mg] = *reinterpret_cast<const f16x8*>(
                wt + (size_t)row * IC + ks * 32 + lhi * 8);
        }
#pragma unroll
        for (int ng = 0; ng < 4; ++ng) {
            const int rr = ng * 16 + llo;                      // node in tile
            const int cc = ks * 4 + lhi;
            b[ng] = *reinterpret_cast<const f16x8*>(
                &sf[(rr * 16 + (cc ^ (rr & 7))) * 8]);
        }
#pragma unroll
        for (int mg = 0; mg < 4; ++mg)
#pragma unroll
            for (int ng = 0; ng < 4; ++ng)
                acc[mg][ng] = __builtin_amdgcn_mfma_f32_16x16x32_f16(
                    a[mg], b[ng], acc[mg][ng], 0, 0, 0);
    }

    // D: col=l&15 (node), row=4*(l>>4)+j (channel). 8B packed stores.
#pragma unroll
    for (int ng = 0; ng < 4; ++ng) {
        const int n = n0 + ng * 16 + llo;
        if (n >= NN) continue;
#pragma unroll
        for (int mg = 0; mg < 4; ++mg) {
            const int ch = w * 64 + mg * 16 + 4 * lhi;
            ushort4 pk;
            pk.x = __half_as_ushort(__float2half(acc[mg][ng][0]));
            pk.y = __half_as_ushort(__float2half(acc[mg][ng][1]));
            pk.z = __half_as_ushort(__float2half(acc[mg][ng][2]));
            pk.w = __half_as_ushort(__float2half(acc[mg][ng][3]));
            *reinterpret_cast<ushort4*>(&Xh[(size_t)n * HC + ch]) = pk;
        }
    }
}

// ---------------------------------------------------------------------------
// Logits: one wave per node; lane l covers channels 4l..4l+3 (head l>>4).
// ---------------------------------------------------------------------------
__global__ __launch_bounds__(256) void logits_kernel(
    const __half* __restrict__ Xh, const float* __restrict__ att_s,
    const float* __restrict__ att_d, float* __restrict__ As,
    float* __restrict__ Ad)
{
    const int gid = blockIdx.x * 256 + threadIdx.x;
    const int n = gid >> 6, l = gid & 63;
    if (n >= NN) return;

    const ushort4 raw = *reinterpret_cast<const ushort4*>(&Xh[(size_t)n * HC + 4 * l]);
    float x0 = __half2float(__ushort_as_half(raw.x));
    float x1 = __half2float(__ushort_as_half(raw.y));
    float x2 = __half2float(__ushort_as_half(raw.z));
    float x3 = __half2float(__ushort_as_half(raw.w));

    const float4 as4 = *reinterpret_cast<const float4*>(att_s + 4 * l);
    const float4 ad4 = *reinterpret_cast<const float4*>(att_d + 4 * l);
    float ps = x0 * as4.x + x1 * as4.y + x2 * as4.z + x3 * as4.w;
    float pd = x0 * ad4.x + x1 * ad4.y + x2 * ad4.z + x3 * ad4.w;
#pragma unroll
    for (int o = 8; o; o >>= 1) {
        ps += __shfl_xor(ps, o);
        pd += __shfl_xor(pd, o);
    }
    if ((l & 15) == 0) {
        As[n * 4 + (l >> 4)] = ps;
        Ad[n * 4 + (l >> 4)] = pd;
    }
}

// ---------------------------------------------------------------------------
// CSR build: histogram, hierarchical scan (3 small kernels), fill
// ---------------------------------------------------------------------------
__global__ __launch_bounds__(256) void hist_kernel(
    const int* __restrict__ ei, int* __restrict__ deg)
{
    const int e = blockIdx.x * 256 + threadIdx.x;
    if (e >= ET) return;
    const int d = (e < NE) ? ei[NE + e] : (e - NE);
    atomicAdd(&deg[d], 1);
}

__global__ __launch_bounds__(256) void scan1(
    const int* __restrict__ deg, int* __restrict__ rowptr, int* __restrict__ bsum)
{
    __shared__ int sh[256];
    const int t = threadIdx.x;
    const int base = blockIdx.x * 1024 + t * 4;
    int4 v = {0, 0, 0, 0};
    if (base + 3 < NN) v = *reinterpret_cast<const int4*>(deg + base);
    else {
        if (base     < NN) v.x = deg[base];
        if (base + 1 < NN) v.y = deg[base + 1];
        if (base + 2 < NN) v.z = deg[base + 2];
    }
    sh[t] = v.x + v.y + v.z + v.w;
    __syncthreads();
    for (int o = 1; o < 256; o <<= 1) {
        const int u = (t >= o) ? sh[t - o] : 0;
        __syncthreads();
        sh[t] += u;
        __syncthreads();
    }
    const int excl = t ? sh[t - 1] : 0;
    int4 e;
    e.x = excl; e.y = excl + v.x; e.z = e.y + v.y; e.w = e.z + v.z;
    if (base + 3 < NN) *reinterpret_cast<int4*>(rowptr + base) = e;
    else {
        if (base     < NN) rowptr[base]     = e.x;
        if (base + 1 < NN) rowptr[base + 1] = e.y;
        if (base + 2 < NN) rowptr[base + 2] = e.z;
    }
    if (t == 255) bsum[blockIdx.x] = sh[255];
}

__global__ void scan2(int* __restrict__ bsum, int* __restrict__ rowptr_end, int nb)
{
    const int t = threadIdx.x;   // 64
    const int v = (t < nb) ? bsum[t] : 0;
    int inc = v;
#pragma unroll
    for (int o = 1; o < 64; o <<= 1) {
        const int u = __shfl_up(inc, o);
        if (t >= o) inc += u;
    }
    if (t < nb) bsum[t] = inc - v;            // exclusive block offset
    if (t == 63) rowptr_end[0] = inc;         // total = ET
}

__global__ __launch_bounds__(256) void scan3(
    int* __restrict__ rowptr, const int* __restrict__ bsum, int* __restrict__ cursor)
{
    const int off  = bsum[blockIdx.x];
    const int base = blockIdx.x * 1024 + threadIdx.x * 4;
#pragma unroll
    for (int i = 0; i < 4; ++i) {
        const int idx = base + i;
        if (idx < NN) {
            const int r = rowptr[idx] + off;
            rowptr[idx] = r;
            cursor[idx] = r;
        }
    }
}

__global__ __launch_bounds__(256) void fill_kernel(
    const int* __restrict__ ei, int* __restrict__ cursor, int* __restrict__ csr_src)
{
    const int e = blockIdx.x * 256 + threadIdx.x;
    if (e >= ET) return;
    int s, d;
    if (e < NE) { s = ei[e]; d = ei[NE + e]; }
    else        { s = e - NE; d = s; }
    csr_src[atomicAdd(&cursor[d], 1)] = s;
}

// ---------------------------------------------------------------------------
// Gather: one wave per dst node (unchanged from R3 — works, no atomics)
// ---------------------------------------------------------------------------
__global__ __launch_bounds__(256) void gather_kernel(
    const int* __restrict__ rowptr, const int* __restrict__ csr_src,
    const float* __restrict__ As, const float* __restrict__ Ad,
    const __half* __restrict__ Xh, const float* __restrict__ bias,
    float* __restrict__ out)
{
    const int gid  = blockIdx.x * 256 + threadIdx.x;
    const int w    = gid >> 6;
    const int lane = gid & 63;
    if (w >= NN) return;

    const int beg = rowptr[w];
    const int end = rowptr[w + 1];
    const int h   = lane >> 4;

    const float4 ad = *reinterpret_cast<const float4*>(&Ad[(size_t)w * 4]);
    float4 acc = {0.f, 0.f, 0.f, 0.f};
    float4 den = {0.f, 0.f, 0.f, 0.f};

    int sj = (beg < end) ? csr_src[beg] : 0;
    for (int j = beg; j < end; ++j) {
        const int s = sj;
        if (j + 1 < end) sj = csr_src[j + 1];

        const float4 a = *reinterpret_cast<const float4*>(&As[(size_t)s * 4]);
        float4 tt;
        tt.x = a.x + ad.x; tt.y = a.y + ad.y; tt.z = a.z + ad.z; tt.w = a.w + ad.w;
        tt.x = tt.x > 0.f ? tt.x : 0.2f * tt.x;
        tt.y = tt.y > 0.f ? tt.y : 0.2f * tt.y;
        tt.z = tt.z > 0.f ? tt.z : 0.2f * tt.z;
        tt.w = tt.w > 0.f ? tt.w : 0.2f * tt.w;
        float4 ex;
        ex.x = __expf(tt.x); ex.y = __expf(tt.y);
        ex.z = __expf(tt.z); ex.w = __expf(tt.w);
        den.x += ex.x; den.y += ex.y; den.z += ex.z; den.w += ex.w;

        const float exh = (h < 2) ? (h == 0 ? ex.x : ex.y)
                                  : (h == 2 ? ex.z : ex.w);

        const float2 raw = *reinterpret_cast<const float2*>(
            Xh + (size_t)s * HC + 4 * lane);
        const __half2* h2 = reinterpret_cast<const __half2*>(&raw);
        const float2 lo = __half22float2(h2[0]);
        const float2 hi = __half22float2(h2[1]);
        acc.x = fmaf(exh, lo.x, acc.x);
        acc.y = fmaf(exh, lo.y, acc.y);
        acc.z = fmaf(exh, hi.x, acc.z);
        acc.w = fmaf(exh, hi.y, acc.w);
    }

    const float dh  = (h < 2) ? (h == 0 ? den.x : den.y)
                              : (h == 2 ? den.z : den.w);
    const float inv = 0.25f * __frcp_rn(dh);
    acc.x *= inv; acc.y *= inv; acc.z *= inv; acc.w *= inv;

    acc.x += __shfl_xor(acc.x, 16); acc.x += __shfl_xor(acc.x, 32);
    acc.y += __shfl_xor(acc.y, 16); acc.y += __shfl_xor(acc.y, 32);
    acc.z += __shfl_xor(acc.z, 16); acc.z += __shfl_xor(acc.z, 32);
    acc.w += __shfl_xor(acc.w, 16); acc.w += __shfl_xor(acc.w, 32);

    if (lane < 16) {
        const float4 b = *reinterpret_cast<const float4*>(&bias[4 * lane]);
        float4 o;
        o.x = acc.x + b.x; o.y = acc.y + b.y;
        o.z = acc.z + b.z; o.w = acc.w + b.w;
        *reinterpret_cast<float4*>(&out[(size_t)w * OC + 4 * lane]) = o;
    }
}

extern "C" void kernel_launch(void* const* d_in, const int* in_sizes, int n_in,
                              void* d_out, int out_size, void* d_ws, size_t ws_size,
                              hipStream_t stream)
{
    const float* feat = (const float*)d_in[0];
    const int*   ei   = (const int*)d_in[1];
    const float* lw   = (const float*)d_in[2];
    const float* as   = (const float*)d_in[3];
    const float* ad   = (const float*)d_in[4];
    const float* bias = (const float*)d_in[5];
    float* out = (float*)d_out;

    constexpr int NSB = (NN + 1023) / 1024;   // 49 scan blocks

    char* ws = (char*)d_ws;
    __half* Xh     = (__half*)ws;  ws += (size_t)NN * HC * 2;
    __half* Wt     = (__half*)ws;  ws += (size_t)HC * IC * 2;
    float*  Asrc   = (float*)ws;   ws += (size_t)NN * 4 * 4;
    float*  Adst   = (float*)ws;   ws += (size_t)NN * 4 * 4;
    int*    deg    = (int*)ws;     ws += (size_t)NN * 4;      // zeroed
    int*    rowptr = (int*)ws;     ws += (size_t)(NN + 1) * 4;
    int*    cursor = (int*)ws;     ws += (size_t)NN * 4;
    int*    bsum   = (int*)ws;     ws += (size_t)64 * 4;
    int*    csrsrc = (int*)ws;     ws += (size_t)ET * 4;

    (void)hipMemsetAsync(deg, 0, sizeof(int) * (size_t)NN, stream);

    prep_wt<<<IC, HC, 0, stream>>>(lw, Wt);
    proj_mfma<<<(NN + 63) / 64, 256, 0, stream>>>(feat, Wt, Xh);
    logits_kernel<<<(NN * 64) / 256, 256, 0, stream>>>(Xh, as, ad, Asrc, Adst);
    hist_kernel<<<(ET + 255) / 256, 256, 0, stream>>>(ei, deg);
    scan1<<<NSB, 256, 0, stream>>>(deg, rowptr, bsum);
    scan2<<<1, 64, 0, stream>>>(bsum, rowptr + NN, NSB);
    scan3<<<NSB, 256, 0, stream>>>(rowptr, bsum, cursor);
    fill_kernel<<<(ET + 255) / 256, 256, 0, stream>>>(ei, cursor, csrsrc);
    gather_kernel<<<(NN * 64 + 255) / 256, 256, 0, stream>>>(
        rowptr, csrsrc, Asrc, Adst, Xh, bias, out);
}

// Round 5
// 204.714 us; speedup vs baseline: 2.3060x; 1.0847x over previous
//
#include <hip/hip_runtime.h>
#include <hip/hip_fp16.h>

typedef _Float16 f16x8 __attribute__((ext_vector_type(8)));
typedef float    f32x4 __attribute__((ext_vector_type(4)));

constexpr int NN = 50000;        // nodes
constexpr int NE = 800000;       // edges (before self-loops)
constexpr int ET = NE + NN;      // edges + self-loops
constexpr int IC = 128;          // in channels
constexpr int HC = 256;          // heads * out_ch
constexpr int OC = 64;           // out channels

// ---------------------------------------------------------------------------
// Prep: Wt[m][k] = lin_w[k][m] as fp16 (A-operand, L2-resident 64KB)
// ---------------------------------------------------------------------------
__global__ void prep_wt(const float* __restrict__ w, __half* __restrict__ wt)
{
    const int k = blockIdx.x;      // 128
    const int m = threadIdx.x;     // 256
    wt[m * IC + k] = __float2half(w[k * HC + m]);
}

// ---------------------------------------------------------------------------
// Proj via MFMA + fused per-head logits.
// Per block: 64 nodes x 256 channels, K=128. Wave w covers channels
// 64w..64w+63 == head w, so the att_src/att_dst dot-reduction for head w
// completes within the wave (shfl over lhi) — no extra kernel, no Xh re-read.
// ---------------------------------------------------------------------------
__global__ __launch_bounds__(256) void proj_mfma(
    const float* __restrict__ feat, const __half* __restrict__ wt,
    const float* __restrict__ att_s, const float* __restrict__ att_d,
    __half* __restrict__ Xh, float* __restrict__ As, float* __restrict__ Ad)
{
    __shared__ _Float16 sf[64 * 128];
    const int t  = threadIdx.x;
    const int w  = t >> 6;
    const int l  = t & 63;
    const int n0 = blockIdx.x * 64;

    // cooperative load: thread t covers 16B-chunks 4*(t&3)..+3 of row t>>2
    {
        const int r  = t >> 2;
        const int gr = min(n0 + r, NN - 1);
        const float* src = feat + (size_t)gr * IC + (t & 3) * 32;
#pragma unroll
        for (int i = 0; i < 4; ++i) {
            const float4 f0 = *reinterpret_cast<const float4*>(src + i * 8);
            const float4 f1 = *reinterpret_cast<const float4*>(src + i * 8 + 4);
            f16x8 hv;
            hv[0] = (_Float16)f0.x; hv[1] = (_Float16)f0.y;
            hv[2] = (_Float16)f0.z; hv[3] = (_Float16)f0.w;
            hv[4] = (_Float16)f1.x; hv[5] = (_Float16)f1.y;
            hv[6] = (_Float16)f1.z; hv[7] = (_Float16)f1.w;
            const int cc = (t & 3) * 4 + i;
            *reinterpret_cast<f16x8*>(&sf[(r * 16 + (cc ^ (r & 7))) * 8]) = hv;
        }
    }
    __syncthreads();

    const int lhi = l >> 4, llo = l & 15;
    f32x4 acc[4][4] = {};   // [mg(channel)][ng(node)]

#pragma unroll
    for (int ks = 0; ks < 4; ++ks) {
        f16x8 a[4], b[4];
#pragma unroll
        for (int mg = 0; mg < 4; ++mg) {
            const int row = w * 64 + mg * 16 + llo;            // channel
            a[mg] = *reinterpret_cast<const f16x8*>(
                wt + (size_t)row * IC + ks * 32 + lhi * 8);
        }
#pragma unroll
        for (int ng = 0; ng < 4; ++ng) {
            const int rr = ng * 16 + llo;                      // node in tile
            const int cc = ks * 4 + lhi;
            b[ng] = *reinterpret_cast<const f16x8*>(
                &sf[(rr * 16 + (cc ^ (rr & 7))) * 8]);
        }
#pragma unroll
        for (int mg = 0; mg < 4; ++mg)
#pragma unroll
            for (int ng = 0; ng < 4; ++ng)
                acc[mg][ng] = __builtin_amdgcn_mfma_f32_16x16x32_f16(
                    a[mg], b[ng], acc[mg][ng], 0, 0, 0);
    }

    // att vectors for this lane's channel slots (reused across ng)
    float4 avs[4], avd[4];
#pragma unroll
    for (int mg = 0; mg < 4; ++mg) {
        const int ch = w * 64 + mg * 16 + 4 * lhi;
        avs[mg] = *reinterpret_cast<const float4*>(att_s + ch);
        avd[mg] = *reinterpret_cast<const float4*>(att_d + ch);
    }

    // D: col=l&15 (node), row=4*(l>>4)+j (channel). 8B packed stores + logits.
#pragma unroll
    for (int ng = 0; ng < 4; ++ng) {
        const int n = n0 + ng * 16 + llo;
        float ps = 0.f, pd = 0.f;
#pragma unroll
        for (int mg = 0; mg < 4; ++mg) {
            const f32x4 v = acc[mg][ng];
            ps += v[0] * avs[mg].x + v[1] * avs[mg].y
                + v[2] * avs[mg].z + v[3] * avs[mg].w;
            pd += v[0] * avd[mg].x + v[1] * avd[mg].y
                + v[2] * avd[mg].z + v[3] * avd[mg].w;
            if (n < NN) {
                const int ch = w * 64 + mg * 16 + 4 * lhi;
                ushort4 pk;
                pk.x = __half_as_ushort(__float2half(v[0]));
                pk.y = __half_as_ushort(__float2half(v[1]));
                pk.z = __half_as_ushort(__float2half(v[2]));
                pk.w = __half_as_ushort(__float2half(v[3]));
                *reinterpret_cast<ushort4*>(&Xh[(size_t)n * HC + ch]) = pk;
            }
        }
        // reduce over lhi (lane bits 4-5)
        ps += __shfl_xor(ps, 16); ps += __shfl_xor(ps, 32);
        pd += __shfl_xor(pd, 16); pd += __shfl_xor(pd, 32);
        if (lhi == 0 && n < NN) {
            As[n * 4 + w] = ps;
            Ad[n * 4 + w] = pd;
        }
    }
}

// ---------------------------------------------------------------------------
// CSR build: histogram, hierarchical scan (3 small kernels), fill
// ---------------------------------------------------------------------------
__global__ __launch_bounds__(256) void hist_kernel(
    const int* __restrict__ ei, int* __restrict__ deg)
{
    const int e = blockIdx.x * 256 + threadIdx.x;
    if (e >= ET) return;
    const int d = (e < NE) ? ei[NE + e] : (e - NE);
    atomicAdd(&deg[d], 1);
}

__global__ __launch_bounds__(256) void scan1(
    const int* __restrict__ deg, int* __restrict__ rowptr, int* __restrict__ bsum)
{
    __shared__ int sh[256];
    const int t = threadIdx.x;
    const int base = blockIdx.x * 1024 + t * 4;
    int4 v = {0, 0, 0, 0};
    if (base + 3 < NN) v = *reinterpret_cast<const int4*>(deg + base);
    else {
        if (base     < NN) v.x = deg[base];
        if (base + 1 < NN) v.y = deg[base + 1];
        if (base + 2 < NN) v.z = deg[base + 2];
    }
    sh[t] = v.x + v.y + v.z + v.w;
    __syncthreads();
    for (int o = 1; o < 256; o <<= 1) {
        const int u = (t >= o) ? sh[t - o] : 0;
        __syncthreads();
        sh[t] += u;
        __syncthreads();
    }
    const int excl = t ? sh[t - 1] : 0;
    int4 e;
    e.x = excl; e.y = excl + v.x; e.z = e.y + v.y; e.w = e.z + v.z;
    if (base + 3 < NN) *reinterpret_cast<int4*>(rowptr + base) = e;
    else {
        if (base     < NN) rowptr[base]     = e.x;
        if (base + 1 < NN) rowptr[base + 1] = e.y;
        if (base + 2 < NN) rowptr[base + 2] = e.z;
    }
    if (t == 255) bsum[blockIdx.x] = sh[255];
}

__global__ void scan2(int* __restrict__ bsum, int* __restrict__ rowptr_end, int nb)
{
    const int t = threadIdx.x;   // 64
    const int v = (t < nb) ? bsum[t] : 0;
    int inc = v;
#pragma unroll
    for (int o = 1; o < 64; o <<= 1) {
        const int u = __shfl_up(inc, o);
        if (t >= o) inc += u;
    }
    if (t < nb) bsum[t] = inc - v;            // exclusive block offset
    if (t == 63) rowptr_end[0] = inc;         // total = ET
}

__global__ __launch_bounds__(256) void scan3(
    int* __restrict__ rowptr, const int* __restrict__ bsum, int* __restrict__ cursor)
{
    const int off  = bsum[blockIdx.x];
    const int base = blockIdx.x * 1024 + threadIdx.x * 4;
#pragma unroll
    for (int i = 0; i < 4; ++i) {
        const int idx = base + i;
        if (idx < NN) {
            const int r = rowptr[idx] + off;
            rowptr[idx] = r;
            cursor[idx] = r;
        }
    }
}

__global__ __launch_bounds__(256) void fill_kernel(
    const int* __restrict__ ei, int* __restrict__ cursor, int* __restrict__ csr_src)
{
    const int e = blockIdx.x * 256 + threadIdx.x;
    if (e >= ET) return;
    int s, d;
    if (e < NE) { s = ei[e]; d = ei[NE + e]; }
    else        { s = e - NE; d = s; }
    csr_src[atomicAdd(&cursor[d], 1)] = s;
}

// ---------------------------------------------------------------------------
// Gather: one wave per dst node; lane group h = lane>>4 handles ONLY head h
// (channels h*64 + 4*(lane&15)..+3 -> same coalesced X address as before).
// Per edge per lane: 1 exp instead of 4, ~1/3 the VALU ops.
// ---------------------------------------------------------------------------
__global__ __launch_bounds__(256) void gather_kernel(
    const int* __restrict__ rowptr, const int* __restrict__ csr_src,
    const float* __restrict__ As, const float* __restrict__ Ad,
    const __half* __restrict__ Xh, const float* __restrict__ bias,
    float* __restrict__ out)
{
    const int gid  = blockIdx.x * 256 + threadIdx.x;
    const int w    = gid >> 6;
    const int lane = gid & 63;
    if (w >= NN) return;

    const int beg = rowptr[w];
    const int end = rowptr[w + 1];
    const int h   = lane >> 4;

    const float adh = Ad[w * 4 + h];
    float4 acc = {0.f, 0.f, 0.f, 0.f};
    float den = 0.f;

    int sj = (beg < end) ? csr_src[beg] : 0;
    for (int j = beg; j < end; ++j) {
        const int s = sj;
        if (j + 1 < end) sj = csr_src[j + 1];

        float lg = As[s * 4 + h] + adh;          // broadcast within group
        lg = lg > 0.f ? lg : 0.2f * lg;
        const float ex = __expf(lg);
        den += ex;

        const float2 raw = *reinterpret_cast<const float2*>(
            Xh + (size_t)s * HC + 4 * lane);
        const __half2* h2 = reinterpret_cast<const __half2*>(&raw);
        const float2 lo = __half22float2(h2[0]);
        const float2 hi = __half22float2(h2[1]);
        acc.x = fmaf(ex, lo.x, acc.x);
        acc.y = fmaf(ex, lo.y, acc.y);
        acc.z = fmaf(ex, hi.x, acc.z);
        acc.w = fmaf(ex, hi.y, acc.w);
    }

    const float inv = 0.25f * __frcp_rn(den);
    acc.x *= inv; acc.y *= inv; acc.z *= inv; acc.w *= inv;

    // sum across the 4 head-lane-groups (lanes l, l^16, l^32, l^48 share channels)
    acc.x += __shfl_xor(acc.x, 16); acc.x += __shfl_xor(acc.x, 32);
    acc.y += __shfl_xor(acc.y, 16); acc.y += __shfl_xor(acc.y, 32);
    acc.z += __shfl_xor(acc.z, 16); acc.z += __shfl_xor(acc.z, 32);
    acc.w += __shfl_xor(acc.w, 16); acc.w += __shfl_xor(acc.w, 32);

    if (lane < 16) {
        const float4 b = *reinterpret_cast<const float4*>(&bias[4 * lane]);
        float4 o;
        o.x = acc.x + b.x; o.y = acc.y + b.y;
        o.z = acc.z + b.z; o.w = acc.w + b.w;
        *reinterpret_cast<float4*>(&out[(size_t)w * OC + 4 * lane]) = o;
    }
}

extern "C" void kernel_launch(void* const* d_in, const int* in_sizes, int n_in,
                              void* d_out, int out_size, void* d_ws, size_t ws_size,
                              hipStream_t stream)
{
    const float* feat = (const float*)d_in[0];
    const int*   ei   = (const int*)d_in[1];
    const float* lw   = (const float*)d_in[2];
    const float* as   = (const float*)d_in[3];
    const float* ad   = (const float*)d_in[4];
    const float* bias = (const float*)d_in[5];
    float* out = (float*)d_out;

    constexpr int NSB = (NN + 1023) / 1024;   // 49 scan blocks

    char* ws = (char*)d_ws;
    __half* Xh     = (__half*)ws;  ws += (size_t)NN * HC * 2;
    __half* Wt     = (__half*)ws;  ws += (size_t)HC * IC * 2;
    float*  Asrc   = (float*)ws;   ws += (size_t)NN * 4 * 4;
    float*  Adst   = (float*)ws;   ws += (size_t)NN * 4 * 4;
    int*    deg    = (int*)ws;     ws += (size_t)NN * 4;      // zeroed
    int*    rowptr = (int*)ws;     ws += (size_t)(NN + 1) * 4;
    int*    cursor = (int*)ws;     ws += (size_t)NN * 4;
    int*    bsum   = (int*)ws;     ws += (size_t)64 * 4;
    int*    csrsrc = (int*)ws;     ws += (size_t)ET * 4;

    (void)hipMemsetAsync(deg, 0, sizeof(int) * (size_t)NN, stream);

    prep_wt<<<IC, HC, 0, stream>>>(lw, Wt);
    proj_mfma<<<(NN + 63) / 64, 256, 0, stream>>>(feat, Wt, as, ad, Xh, Asrc, Adst);
    hist_kernel<<<(ET + 255) / 256, 256, 0, stream>>>(ei, deg);
    scan1<<<NSB, 256, 0, stream>>>(deg, rowptr, bsum);
    scan2<<<1, 64, 0, stream>>>(bsum, rowptr + NN, NSB);
    scan3<<<NSB, 256, 0, stream>>>(rowptr, bsum, cursor);
    fill_kernel<<<(ET + 255) / 256, 256, 0, stream>>>(ei, cursor, csrsrc);
    gather_kernel<<<(NN * 64 + 255) / 256, 256, 0, stream>>>(
        rowptr, csrsrc, Asrc, Adst, Xh, bias, out);
}